// Round 1
// baseline (141.819 us; speedup 1.0000x reference)
//
#include <hip/hip_runtime.h>
#include <cstdint>
#include <cstddef>

// Problem constants
#define FF 64
#define EE 64
#define HH 8
#define PP 512
#define MM 16384   // B*T = 64*256
#define KK 1024    // 2 * F * H  (both branches concatenated)

typedef __bf16 bf16x8 __attribute__((ext_vector_type(8)));
typedef float  floatx4 __attribute__((ext_vector_type(4)));

// float -> bf16 (RNE), bit-level to avoid header API drift
__device__ __forceinline__ unsigned short f2bf(float f) {
    unsigned int u = __float_as_uint(f);
    u += 0x7FFFu + ((u >> 16) & 1u);
    return (unsigned short)(u >> 16);
}

__device__ __forceinline__ unsigned pack2(unsigned short a, unsigned short b) {
    return (unsigned)a | ((unsigned)b << 16);
}

// async global->LDS, 16B per lane; LDS dest = wave-uniform base + lane*16
__device__ __forceinline__ void gl_lds16(const unsigned short* g, unsigned short* s) {
    __builtin_amdgcn_global_load_lds(
        (__attribute__((address_space(1))) void*)(void*)g,
        (__attribute__((address_space(3))) void*)s,
        16, 0, 0);
}

// ---------------------------------------------------------------------------
// Phase 1: BmatT[n][k] (bf16, k-contiguous), k = br*512 + f*8 + h
//   BmatT[n][br,f,h] = sum_e w2[f,h,e] * W[(f*64+e)*512 + n]
// One block per (br, f). 256 threads: thread owns columns n=tid and n=tid+256.
// ---------------------------------------------------------------------------
__global__ __launch_bounds__(256) void combine_kernel(
    const float* __restrict__ w2v, const float* __restrict__ w2t,
    const float* __restrict__ wx,  const float* __restrict__ wt,
    unsigned short* __restrict__ BmatT)
{
    const int br = blockIdx.x >> 6;
    const int f  = blockIdx.x & 63;
    const float* __restrict__ w2 = br ? w2t : w2v;   // [F][H][E]
    const float* __restrict__ W  = br ? wt  : wx;    // [F*E][P]
    __shared__ float w2s[HH * EE];
    const int tid = threadIdx.x;
    for (int i = tid; i < HH * EE; i += 256) w2s[i] = w2[f * HH * EE + i];
    __syncthreads();

    float acc0[HH] = {0,0,0,0,0,0,0,0};
    float acc1[HH] = {0,0,0,0,0,0,0,0};
    const float* Wrow = W + (size_t)f * EE * PP;
    for (int e = 0; e < EE; ++e) {
        const float wv0 = Wrow[(size_t)e * PP + tid];
        const float wv1 = Wrow[(size_t)e * PP + tid + 256];
        #pragma unroll
        for (int h = 0; h < HH; ++h) {
            const float c = w2s[h * EE + e];
            acc0[h] = __builtin_fmaf(c, wv0, acc0[h]);
            acc1[h] = __builtin_fmaf(c, wv1, acc1[h]);
        }
    }
    const int kbase = br * 512 + f * 8;
    uint4 v0, v1;
    v0.x = pack2(f2bf(acc0[0]), f2bf(acc0[1]));
    v0.y = pack2(f2bf(acc0[2]), f2bf(acc0[3]));
    v0.z = pack2(f2bf(acc0[4]), f2bf(acc0[5]));
    v0.w = pack2(f2bf(acc0[6]), f2bf(acc0[7]));
    v1.x = pack2(f2bf(acc1[0]), f2bf(acc1[1]));
    v1.y = pack2(f2bf(acc1[2]), f2bf(acc1[3]));
    v1.z = pack2(f2bf(acc1[4]), f2bf(acc1[5]));
    v1.w = pack2(f2bf(acc1[6]), f2bf(acc1[7]));
    *reinterpret_cast<uint4*>(&BmatT[(size_t)tid        * KK + kbase]) = v0;
    *reinterpret_cast<uint4*>(&BmatT[(size_t)(tid+256)  * KK + kbase]) = v1;
}

// ---------------------------------------------------------------------------
// Phase 2: Hc[row][k] (bf16), k = br*512 + f*8 + h
//   Hc = tanh(in[row,f]*w1[f,h] + b1[f,h]);   in = x (br=0) or time (br=1)
// Each thread produces one (row, br, f): 8 contiguous bf16 = one 16B store.
// ---------------------------------------------------------------------------
__global__ __launch_bounds__(256) void hfeat_kernel(
    const float* __restrict__ x,   const float* __restrict__ tmv,
    const float* __restrict__ w1v, const float* __restrict__ b1v,
    const float* __restrict__ w1t, const float* __restrict__ b1t,
    unsigned short* __restrict__ Hc)
{
    const int g   = blockIdx.x * 256 + threadIdx.x;  // chunk id (8 elems each)
    const int row = g >> 7;       // 128 chunks per row
    const int j   = g & 127;
    const int br  = j >> 6;       // wave-uniform (64-thread granularity)
    const int f   = j & 63;
    const float val = br ? tmv[(size_t)row * FF + f] : x[(size_t)row * FF + f];
    const float* w1 = br ? w1t : w1v;    // [F][H]
    const float* b1 = br ? b1t : b1v;
    const float4 wa = reinterpret_cast<const float4*>(w1)[f * 2];
    const float4 wb = reinterpret_cast<const float4*>(w1)[f * 2 + 1];
    const float4 ba = reinterpret_cast<const float4*>(b1)[f * 2];
    const float4 bb = reinterpret_cast<const float4*>(b1)[f * 2 + 1];
    float hv[8];
    hv[0] = tanhf(__builtin_fmaf(val, wa.x, ba.x));
    hv[1] = tanhf(__builtin_fmaf(val, wa.y, ba.y));
    hv[2] = tanhf(__builtin_fmaf(val, wa.z, ba.z));
    hv[3] = tanhf(__builtin_fmaf(val, wa.w, ba.w));
    hv[4] = tanhf(__builtin_fmaf(val, wb.x, bb.x));
    hv[5] = tanhf(__builtin_fmaf(val, wb.y, bb.y));
    hv[6] = tanhf(__builtin_fmaf(val, wb.z, bb.z));
    hv[7] = tanhf(__builtin_fmaf(val, wb.w, bb.w));
    uint4 v;
    v.x = pack2(f2bf(hv[0]), f2bf(hv[1]));
    v.y = pack2(f2bf(hv[2]), f2bf(hv[3]));
    v.z = pack2(f2bf(hv[4]), f2bf(hv[5]));
    v.w = pack2(f2bf(hv[6]), f2bf(hv[7]));
    *reinterpret_cast<uint4*>(&Hc[(size_t)row * KK + br * 512 + f * 8]) = v;
}

// ---------------------------------------------------------------------------
// Phase 3: out[m][n] = sum_k Hc[m][k]*BmatT[n][k] + bx[n] + bt[n]
// 128x128 block tile, BK=64, 256 threads = 4 waves, each wave a 64x64 quadrant
// of 4x4 16x16x32-bf16 MFMA tiles. Staging via global_load_lds width=16.
// Verified layouts: A/B frag elem j -> k=(lane>>4)*8+j, m/n=lane&15;
// C/D: col=lane&15, row=(lane>>4)*4+r.
// ---------------------------------------------------------------------------
__global__ __launch_bounds__(256) void gemm_kernel(
    const unsigned short* __restrict__ A,   // Hc    [MM][KK]
    const unsigned short* __restrict__ Bt,  // BmatT [PP][KK]
    const float* __restrict__ bx, const float* __restrict__ bt,
    float* __restrict__ out)                 // [MM][PP]
{
    __shared__ unsigned short As[128 * 64];  // [m][k], 16 KB
    __shared__ unsigned short Bs[128 * 64];  // [n][k], 16 KB
    const int tid  = threadIdx.x;
    const int wave = tid >> 6;
    const int lane = tid & 63;
    const int m0 = blockIdx.y * 128;
    const int n0 = blockIdx.x * 128;
    const int wr = wave >> 1;   // wave row quadrant (0..1)
    const int wc = wave & 1;    // wave col quadrant (0..1)
    const int q  = lane >> 4;
    const int ml = lane & 15;
    const int lr = lane >> 3;        // 0..7: row within 8-row segment
    const int lk = (lane & 7) * 8;   // k offset within 64

    floatx4 acc[4][4];
    #pragma unroll
    for (int i = 0; i < 4; ++i)
        #pragma unroll
        for (int j = 0; j < 4; ++j)
            acc[i][j] = (floatx4){0.f, 0.f, 0.f, 0.f};

    for (int k0 = 0; k0 < KK; k0 += 64) {
        #pragma unroll
        for (int i = 0; i < 4; ++i) {
            const int seg = wave * 4 + i;        // 0..15, disjoint per (wave,i)
            const int r = seg * 8 + lr;          // tile row 0..127
            gl_lds16(&A [(size_t)(m0 + r) * KK + k0 + lk], &As[seg * 512]);
            gl_lds16(&Bt[(size_t)(n0 + r) * KK + k0 + lk], &Bs[seg * 512]);
        }
        __syncthreads();   // drains vmcnt: staged data visible
        #pragma unroll
        for (int kk = 0; kk < 64; kk += 32) {
            bf16x8 af[4], bfr[4];
            #pragma unroll
            for (int mt = 0; mt < 4; ++mt)
                af[mt] = *reinterpret_cast<const bf16x8*>(
                    &As[(wr * 64 + mt * 16 + ml) * 64 + kk + q * 8]);
            #pragma unroll
            for (int nt = 0; nt < 4; ++nt)
                bfr[nt] = *reinterpret_cast<const bf16x8*>(
                    &Bs[(wc * 64 + nt * 16 + ml) * 64 + kk + q * 8]);
            #pragma unroll
            for (int mt = 0; mt < 4; ++mt)
                #pragma unroll
                for (int nt = 0; nt < 4; ++nt)
                    acc[mt][nt] = __builtin_amdgcn_mfma_f32_16x16x32_bf16(
                        af[mt], bfr[nt], acc[mt][nt], 0, 0, 0);
        }
        __syncthreads();   // before next iteration overwrites LDS
    }

    #pragma unroll
    for (int nt = 0; nt < 4; ++nt) {
        const int n = n0 + wc * 64 + nt * 16 + ml;
        const float bias = bx[n] + bt[n];
        #pragma unroll
        for (int mt = 0; mt < 4; ++mt) {
            const int mb = m0 + wr * 64 + mt * 16 + q * 4;
            #pragma unroll
            for (int r = 0; r < 4; ++r)
                out[(size_t)(mb + r) * PP + n] = acc[mt][nt][r] + bias;
        }
    }
}

// ---------------------------------------------------------------------------
extern "C" void kernel_launch(void* const* d_in, const int* in_sizes, int n_in,
                              void* d_out, int out_size, void* d_ws, size_t ws_size,
                              hipStream_t stream)
{
    const float* x   = (const float*)d_in[0];
    const float* tmv = (const float*)d_in[1];
    const float* w1v = (const float*)d_in[2];
    const float* b1v = (const float*)d_in[3];
    const float* w2v = (const float*)d_in[4];
    const float* w1t = (const float*)d_in[5];
    const float* b1t = (const float*)d_in[6];
    const float* w2t = (const float*)d_in[7];
    const float* wx  = (const float*)d_in[8];
    const float* bx  = (const float*)d_in[9];
    const float* wt  = (const float*)d_in[10];
    const float* bt  = (const float*)d_in[11];
    float* out = (float*)d_out;

    // ws layout: [0, 1MB) BmatT bf16 [512][1024]; [1MB, +33.5MB) Hc bf16 [16384][1024]
    unsigned short* Bws = (unsigned short*)d_ws;
    unsigned short* Hws = (unsigned short*)((char*)d_ws + (1u << 20));

    combine_kernel<<<128, 256, 0, stream>>>(w2v, w2t, wx, wt, Bws);
    hfeat_kernel<<<MM * KK / 8 / 256, 256, 0, stream>>>(x, tmv, w1v, b1v, w1t, b1t, Hws);
    gemm_kernel<<<dim3(PP / 128, MM / 128), 256, 0, stream>>>(Hws, Bws, bx, bt, out);
}

// Round 2
// 127.280 us; speedup vs baseline: 1.1142x; 1.1142x over previous
//
#include <hip/hip_runtime.h>
#include <cstdint>
#include <cstddef>

// Problem constants
#define FF 64
#define EE 64
#define HH 8
#define PP 512
#define MM 16384   // B*T = 64*256
#define KK 1024    // 2 * F * H  (both branches concatenated)

typedef __bf16 bf16x8 __attribute__((ext_vector_type(8)));
typedef float  floatx4 __attribute__((ext_vector_type(4)));

// float -> bf16 (RNE)
__device__ __forceinline__ unsigned short f2bf(float f) {
    unsigned int u = __float_as_uint(f);
    u += 0x7FFFu + ((u >> 16) & 1u);
    return (unsigned short)(u >> 16);
}

__device__ __forceinline__ unsigned pack2(unsigned short a, unsigned short b) {
    return (unsigned)a | ((unsigned)b << 16);
}

// fast tanh: 1 - 2/(exp2(2x*log2e)+1); v_exp/v_rcp are ~1ulp -> err ~1e-6,
// far below bf16 quantization (2^-8) and the 2.58e-2 harness threshold.
__device__ __forceinline__ float fast_tanh(float x) {
    float e, r;
    asm("v_exp_f32 %0, %1" : "=v"(e) : "v"(x * 2.8853900817779268f));
    float d = e + 1.0f;
    asm("v_rcp_f32 %0, %1" : "=v"(r) : "v"(d));
    return __builtin_fmaf(-2.0f, r, 1.0f);
}

// async global->LDS, 16B per lane; LDS dest = wave-uniform base + lane*16
__device__ __forceinline__ void gl_lds16(const unsigned short* g, unsigned short* s) {
    __builtin_amdgcn_global_load_lds(
        (__attribute__((address_space(1))) void*)(void*)g,
        (__attribute__((address_space(3))) void*)s,
        16, 0, 0);
}

// ---------------------------------------------------------------------------
// Fused prep kernel.
//  Blocks [0,256): combine  — BmatT[n][k], k = br*512+f*8+h, bf16:
//     BmatT[n][br,f,h] = sum_e w2[f,h,e] * W[(f*64+e)*512 + n]
//     block = (br, f, n-half); thread owns one n column.
//  Blocks [256, 256+8192): hfeat — Hc[row][k] bf16:
//     Hc[row][br,f,h] = fast_tanh(in[row,f]*w1[f,h]+b1[f,h])
//     one thread per (row, br, f) -> 8 contiguous bf16 = one 16B store.
// Independent work fused so the latency-bound combine overlaps hfeat.
// ---------------------------------------------------------------------------
__global__ __launch_bounds__(256) void prep_kernel(
    const float* __restrict__ x,   const float* __restrict__ tmv,
    const float* __restrict__ w1v, const float* __restrict__ b1v,
    const float* __restrict__ w1t, const float* __restrict__ b1t,
    const float* __restrict__ w2v, const float* __restrict__ w2t,
    const float* __restrict__ wx,  const float* __restrict__ wt,
    unsigned short* __restrict__ BmatT, unsigned short* __restrict__ Hc)
{
    const int tid = threadIdx.x;
    if (blockIdx.x < 256) {
        // ---- combine ----
        const int bid = blockIdx.x;
        const int br = bid >> 7;
        const int f  = (bid >> 1) & 63;
        const int nh = bid & 1;
        const float* __restrict__ w2 = br ? w2t : w2v;   // [F][H][E]
        const float* __restrict__ W  = br ? wt  : wx;    // [F*E][P]
        __shared__ float w2s[HH * EE];
        for (int i = tid; i < HH * EE; i += 256) w2s[i] = w2[f * HH * EE + i];
        __syncthreads();
        const int n = nh * 256 + tid;
        float acc[HH] = {0,0,0,0,0,0,0,0};
        const float* Wcol = W + (size_t)f * EE * PP + n;
        #pragma unroll 8
        for (int e = 0; e < EE; ++e) {
            const float wv = Wcol[(size_t)e * PP];
            #pragma unroll
            for (int h = 0; h < HH; ++h)
                acc[h] = __builtin_fmaf(w2s[h * EE + e], wv, acc[h]);
        }
        uint4 v;
        v.x = pack2(f2bf(acc[0]), f2bf(acc[1]));
        v.y = pack2(f2bf(acc[2]), f2bf(acc[3]));
        v.z = pack2(f2bf(acc[4]), f2bf(acc[5]));
        v.w = pack2(f2bf(acc[6]), f2bf(acc[7]));
        *reinterpret_cast<uint4*>(&BmatT[(size_t)n * KK + br * 512 + f * 8]) = v;
    } else {
        // ---- hfeat ----
        const int g   = (blockIdx.x - 256) * 256 + tid;  // chunk id
        const int row = g >> 7;
        const int j   = g & 127;
        const int br  = j >> 6;     // wave-uniform
        const int f   = j & 63;
        const float val = br ? tmv[(size_t)row * FF + f] : x[(size_t)row * FF + f];
        const float* w1 = br ? w1t : w1v;
        const float* b1 = br ? b1t : b1v;
        const float4 wa = reinterpret_cast<const float4*>(w1)[f * 2];
        const float4 wb = reinterpret_cast<const float4*>(w1)[f * 2 + 1];
        const float4 ba = reinterpret_cast<const float4*>(b1)[f * 2];
        const float4 bb = reinterpret_cast<const float4*>(b1)[f * 2 + 1];
        float hv[8];
        hv[0] = fast_tanh(__builtin_fmaf(val, wa.x, ba.x));
        hv[1] = fast_tanh(__builtin_fmaf(val, wa.y, ba.y));
        hv[2] = fast_tanh(__builtin_fmaf(val, wa.z, ba.z));
        hv[3] = fast_tanh(__builtin_fmaf(val, wa.w, ba.w));
        hv[4] = fast_tanh(__builtin_fmaf(val, wb.x, bb.x));
        hv[5] = fast_tanh(__builtin_fmaf(val, wb.y, bb.y));
        hv[6] = fast_tanh(__builtin_fmaf(val, wb.z, bb.z));
        hv[7] = fast_tanh(__builtin_fmaf(val, wb.w, bb.w));
        uint4 v;
        v.x = pack2(f2bf(hv[0]), f2bf(hv[1]));
        v.y = pack2(f2bf(hv[2]), f2bf(hv[3]));
        v.z = pack2(f2bf(hv[4]), f2bf(hv[5]));
        v.w = pack2(f2bf(hv[6]), f2bf(hv[7]));
        *reinterpret_cast<uint4*>(&Hc[(size_t)row * KK + br * 512 + f * 8]) = v;
    }
}

// ---------------------------------------------------------------------------
// GEMM: out[m][n] = sum_k Hc[m][k]*BmatT[n][k] + bx[n] + bt[n]
// 128x128 tile, BK=64, 4 waves each a 64x64 quadrant of 4x4 16x16x32 MFMAs.
// LDS physical layout XOR-swizzled: row r's logical 16B chunk c lives at
// physical chunk c^(r&7)  -> ds_read_b128 with 128B row stride hits all 32
// banks (2 lanes/bank = free, m136) instead of 16-way conflicts.
// Staging permutes the *global* k-offset per lane (LDS slot is forced to
// base+lane*16 by global_load_lds).
// grid.x = m-tiles (128), grid.y = n-tiles (4): the 4 n-tiles of one m-stripe
// have linear ids = x + 128*y = x (mod 8) -> same XCD -> A served from L2.
// ---------------------------------------------------------------------------
__global__ __launch_bounds__(256) void gemm_kernel(
    const unsigned short* __restrict__ A,   // Hc    [MM][KK]
    const unsigned short* __restrict__ Bt,  // BmatT [PP][KK]
    const float* __restrict__ bx, const float* __restrict__ bt,
    float* __restrict__ out)                 // [MM][PP]
{
    __shared__ unsigned short As[128 * 64];  // 16 KB
    __shared__ unsigned short Bs[128 * 64];  // 16 KB
    const int tid  = threadIdx.x;
    const int wave = tid >> 6;
    const int lane = tid & 63;
    const int m0 = blockIdx.x * 128;
    const int n0 = blockIdx.y * 128;
    const int wr = wave >> 1;
    const int wc = wave & 1;
    const int q   = lane >> 4;
    const int ml  = lane & 15;
    const int mlx = ml & 7;          // row&7 for this lane's frag rows
    const int lr  = lane >> 3;            // 0..7 row within 8-row segment
    const int lkg = ((lane & 7) ^ lr) * 8; // swizzled global k-offset (shorts)

    floatx4 acc[4][4];
    #pragma unroll
    for (int i = 0; i < 4; ++i)
        #pragma unroll
        for (int j = 0; j < 4; ++j)
            acc[i][j] = (floatx4){0.f, 0.f, 0.f, 0.f};

    for (int k0 = 0; k0 < KK; k0 += 64) {
        #pragma unroll
        for (int i = 0; i < 4; ++i) {
            const int seg = wave * 4 + i;
            const int r = seg * 8 + lr;
            gl_lds16(&A [(size_t)(m0 + r) * KK + k0 + lkg], &As[seg * 512]);
            gl_lds16(&Bt[(size_t)(n0 + r) * KK + k0 + lkg], &Bs[seg * 512]);
        }
        __syncthreads();
        #pragma unroll
        for (int kk = 0; kk < 64; kk += 32) {
            const int cl = (kk >> 3) + q;          // logical chunk 0..7
            const int co = (cl ^ mlx) * 8;          // swizzled offset (shorts)
            bf16x8 af[4], bfr[4];
            #pragma unroll
            for (int mt = 0; mt < 4; ++mt)
                af[mt] = *reinterpret_cast<const bf16x8*>(
                    &As[(wr * 64 + mt * 16 + ml) * 64 + co]);
            #pragma unroll
            for (int nt = 0; nt < 4; ++nt)
                bfr[nt] = *reinterpret_cast<const bf16x8*>(
                    &Bs[(wc * 64 + nt * 16 + ml) * 64 + co]);
            #pragma unroll
            for (int mt = 0; mt < 4; ++mt)
                #pragma unroll
                for (int nt = 0; nt < 4; ++nt)
                    acc[mt][nt] = __builtin_amdgcn_mfma_f32_16x16x32_bf16(
                        af[mt], bfr[nt], acc[mt][nt], 0, 0, 0);
        }
        __syncthreads();
    }

    #pragma unroll
    for (int nt = 0; nt < 4; ++nt) {
        const int n = n0 + wc * 64 + nt * 16 + ml;
        const float bias = bx[n] + bt[n];
        #pragma unroll
        for (int mt = 0; mt < 4; ++mt) {
            const int mb = m0 + wr * 64 + mt * 16 + q * 4;
            #pragma unroll
            for (int r = 0; r < 4; ++r)
                out[(size_t)(mb + r) * PP + n] = acc[mt][nt][r] + bias;
        }
    }
}

// ---------------------------------------------------------------------------
extern "C" void kernel_launch(void* const* d_in, const int* in_sizes, int n_in,
                              void* d_out, int out_size, void* d_ws, size_t ws_size,
                              hipStream_t stream)
{
    const float* x   = (const float*)d_in[0];
    const float* tmv = (const float*)d_in[1];
    const float* w1v = (const float*)d_in[2];
    const float* b1v = (const float*)d_in[3];
    const float* w2v = (const float*)d_in[4];
    const float* w1t = (const float*)d_in[5];
    const float* b1t = (const float*)d_in[6];
    const float* w2t = (const float*)d_in[7];
    const float* wx  = (const float*)d_in[8];
    const float* bx  = (const float*)d_in[9];
    const float* wt  = (const float*)d_in[10];
    const float* bt  = (const float*)d_in[11];
    float* out = (float*)d_out;

    // ws: [0,1MB) BmatT bf16 [512][1024]; [1MB,+33.5MB) Hc bf16 [16384][1024]
    unsigned short* Bws = (unsigned short*)d_ws;
    unsigned short* Hws = (unsigned short*)((char*)d_ws + (1u << 20));

    prep_kernel<<<256 + MM * KK / 8 / 256, 256, 0, stream>>>(
        x, tmv, w1v, b1v, w1t, b1t, w2v, w2t, wx, wt, Bws, Hws);
    gemm_kernel<<<dim3(MM / 128, PP / 128), 256, 0, stream>>>(Hws, Bws, bx, bt, out);
}